// Round 6
// baseline (3360.421 us; speedup 1.0000x reference)
//
#include <hip/hip_runtime.h>
#include <math.h>

typedef __bf16 bf16x8 __attribute__((ext_vector_type(8)));
typedef float f32x4 __attribute__((ext_vector_type(4)));
typedef unsigned int u32x4 __attribute__((ext_vector_type(4)));
typedef unsigned long long u64;

constexpr int QQ = 1027;   // states
constexpr int SS = 26;     // alphabet
constexpr int TT = 512;    // sequence length
constexpr int NB = 256;    // batch
constexpr int KP = 1056;   // K padded (mult of 32)
constexpr int NP = 1040;   // N padded (65 tiles of 16)
constexpr int BTS = 1040;  // Bt row stride (floats)
constexpr int NSL = 13;    // N slices (5 tiles = 80 cols each)
constexpr int NBB = 16;    // batch blocks
constexpr int MB = 16;     // batch rows per block
constexpr int NWV = 5;     // waves per WG (1 N-tile each)
constexpr int CBLK = NWV * 64;       // 320
constexpr int KSTEPS = KP / 32;      // 33
constexpr int BUFN = NB * KP;        // bf16 elems per alpha buffer
constexpr int RQ = KP / 4;           // 264 u64 per alpha row
constexpr int LQ = RQ + 2;           // 266 u64 LDS row stride (2128B)
constexpr int PSE = NBB * NSL * MB;  // 3328 tag-u64 per slot

__device__ __forceinline__ unsigned short f2bf(float f) {
  union { float f; unsigned u; } v; v.f = f;
  return (unsigned short)((v.u + 0x7fffu + ((v.u >> 16) & 1u)) >> 16);
}

__device__ __forceinline__ u64 ald8(const u64* p) {
  return __hip_atomic_load((u64*)p, __ATOMIC_RELAXED, __HIP_MEMORY_SCOPE_AGENT);
}
__device__ __forceinline__ void ast8(u64* p, u64 v) {
  __hip_atomic_store(p, v, __ATOMIC_RELAXED, __HIP_MEMORY_SCOPE_AGENT);
}

// Spin until the (s5|tag) word carries tag==texp; returns s5.
// Trailing compiler barrier keeps subsequent loads from hoisting above the gate.
__device__ __forceinline__ float spin_tag(const u64* p, unsigned texp) {
  u64 v = ald8(p);
  while ((unsigned)(v >> 32) != texp) v = ald8(p);
  asm volatile("" ::: "memory");
  union { unsigned u; float f; } w; w.u = (unsigned)v;
  return w.f;
}

__global__ void k_zero(u32x4* p, int n) {
  int i = blockIdx.x * blockDim.x + threadIdx.x;
  if (i < n) p[i] = (u32x4){0u, 0u, 0u, 0u};
}

__global__ void k_prep_init(const float* __restrict__ il, float* __restrict__ ip) {
  __shared__ float red[1024];
  int tid = threadIdx.x;
  float m = -1e30f;
  for (int q = tid; q < QQ; q += 1024) m = fmaxf(m, il[q]);
  red[tid] = m; __syncthreads();
  for (int off = 512; off > 0; off >>= 1) {
    if (tid < off) red[tid] = fmaxf(red[tid], red[tid + off]);
    __syncthreads();
  }
  m = red[0]; __syncthreads();
  float s = 0.f;
  for (int q = tid; q < QQ; q += 1024) s += expf(il[q] - m);
  red[tid] = s; __syncthreads();
  for (int off = 512; off > 0; off >>= 1) {
    if (tid < off) red[tid] += red[tid + off];
    __syncthreads();
  }
  s = red[0];
  float inv = 1.0f / s;
  for (int q = tid; q < QQ; q += 1024) ip[q] = expf(il[q] - m) * inv;
}

__global__ void k_prep_B(const float* __restrict__ bl, float* __restrict__ bt) {
  int q = blockIdx.x * blockDim.x + threadIdx.x;
  if (q >= QQ) return;
  const float* row = bl + (size_t)q * SS;
  float m = -1e30f;
  for (int c = 0; c < SS; ++c) m = fmaxf(m, row[c]);
  float s = 0.f;
  for (int c = 0; c < SS; ++c) s += expf(row[c] - m);
  float inv = 1.0f / s;
  for (int c = 0; c < SS; ++c) bt[c * BTS + q] = expf(row[c] - m) * inv;
}

// Row r of A -> column r of A^T[n][k] (bf16)
__global__ void k_prep_A(const float* __restrict__ al, unsigned short* __restrict__ at) {
  int r = blockIdx.x;
  const float* row = al + (size_t)r * QQ;
  __shared__ float red[256];
  int tid = threadIdx.x;
  float m = -1e30f;
  for (int n = tid; n < QQ; n += 256) m = fmaxf(m, row[n]);
  red[tid] = m; __syncthreads();
  for (int off = 128; off > 0; off >>= 1) {
    if (tid < off) red[tid] = fmaxf(red[tid], red[tid + off]);
    __syncthreads();
  }
  m = red[0]; __syncthreads();
  float s = 0.f;
  for (int n = tid; n < QQ; n += 256) s += expf(row[n] - m);
  red[tid] = s; __syncthreads();
  for (int off = 128; off > 0; off >>= 1) {
    if (tid < off) red[tid] += red[tid + off];
    __syncthreads();
  }
  s = red[0];
  float inv = 1.0f / s;
  for (int n = tid; n < QQ; n += 256) at[(size_t)n * KP + r] = f2bf(expf(row[n] - m) * inv);
}

// f0 = init * E[:,0] (unnormalized) into buf0 + tagged per-slice row-sums (tag=0)
__global__ void k_init_step(const int* __restrict__ seq, const float* __restrict__ ip,
                            const float* __restrict__ Bt, unsigned short* __restrict__ buf0,
                            u64* __restrict__ psumE) {
  int b = blockIdx.x, tid = threadIdx.x;
  __shared__ float sp[16];
  if (tid < 16) sp[tid] = 0.f;
  __syncthreads();
  int c0 = seq[b * TT];
  for (int q = tid; q < NP; q += 256) {
    float v = ip[q] * Bt[c0 * BTS + q];   // ip[q>=QQ]=0, Bt[.,q>=QQ]=0
    buf0[(size_t)b * KP + q] = f2bf(v);
    atomicAdd(&sp[q / 80], v);
  }
  __syncthreads();
  if (tid < NSL) {
    union { float f; unsigned u; } w; w.f = sp[tid];
    psumE[(size_t)(b / MB) * (NSL * MB) + tid * MB + (b % MB)] = (u64)w.u;  // tag 0
  }
}

__global__ __launch_bounds__(CBLK, 2) void k_hmm_coop(
    const int* __restrict__ seq, const unsigned short* __restrict__ At,
    const float* __restrict__ Bt, unsigned short* __restrict__ bufB,
    u64* __restrict__ psumE, float* __restrict__ out) {
  __shared__ u64 aldsq[MB * LQ];          // 34 KB: this block's alpha (bf16)
  __shared__ float srow[MB][14];          // per-row per-slice scale partials
  __shared__ float inv_lds[MB];
  __shared__ int chars[MB];
  __shared__ float spart[MB][NWV];

  const int tid = threadIdx.x, wg = blockIdx.x;
  const int bb = wg % NBB, sl = wg / NBB; // 13 slice-WGs per batch block
  const int lane = tid & 63, wv = tid >> 6;
  const int lrow = lane >> 4, lcol = lane & 15;
  const int n0w = (sl * NWV + wv) * 16;   // this wave's 16-col tile base
  const int r20 = tid / 20, i20 = tid % 20;       // chunks 0-11: 20 u64/row
  const int r24a = tid / 24, i24a = tid % 24;     // chunk 12: 24 u64/row
  const int r24b = (tid + 320) / 24, i24b = (tid + 320) % 24;

  // step-invariant At fragments in registers (132 VGPRs)
  u32x4 atr[KSTEPS];
  {
    const u32x4* atp = (const u32x4*)(At + (size_t)(n0w + lcol) * KP + 8 * lrow);
#pragma unroll
    for (int ks = 0; ks < KSTEPS; ++ks) atr[ks] = atp[4 * ks];
  }

  float ll = 0.f;

  for (int t = 1; t < TT; ++t) {
    const int rd = (t - 1) % 3, wri = t % 3;
    const unsigned texp = (unsigned)(t - 1);
    const u64* tagb = psumE + ((size_t)rd * NBB + bb) * (NSL * MB);
    const u64* ain = (const u64*)(bufB + (size_t)rd * BUFN) + (size_t)bb * MB * RQ;
    u64* wbuf8 = (u64*)(bufB + (size_t)wri * BUFN);

    int ch = 0;
    if (tid < MB) ch = seq[(bb * MB + tid) * TT + t];  // issue early (L2)

    // --- gated, pipelined chunk loads; gate value doubles as the psum
    float myps = 0.f;
    u64 av[12], avA, avB = 0;
#pragma unroll
    for (int c = 0; c < 12; ++c) {
      float s5 = spin_tag(tagb + c * MB + r20, texp);
      if (i20 == c) myps = s5;
      av[c] = ald8(ain + (size_t)r20 * RQ + c * 20 + i20);
    }
    if (i20 == 12) myps = spin_tag(tagb + 12 * MB + r20, texp);
    (void)spin_tag(tagb + 12 * MB + r24a, texp);
    avA = ald8(ain + (size_t)r24a * RQ + 240 + i24a);
    if (tid < 64) {
      (void)spin_tag(tagb + 12 * MB + r24b, texp);
      avB = ald8(ain + (size_t)r24b * RQ + 240 + i24b);
    }

    if (i20 < 13) srow[r20][i20] = myps;
    // --- stage alpha into LDS
#pragma unroll
    for (int c = 0; c < 12; ++c) aldsq[r20 * LQ + c * 20 + i20] = av[c];
    aldsq[r24a * LQ + 240 + i24a] = avA;
    if (tid < 64) aldsq[r24b * LQ + 240 + i24b] = avB;
    __syncthreads();  // stage-bar

    // --- k-loop: A = At (regs), B = alpha (LDS)
    const u32x4* ap = ((const u32x4*)aldsq) + lcol * (LQ / 2) + lrow;
    f32x4 acc = (f32x4){0.f, 0.f, 0.f, 0.f};
#pragma unroll
    for (int ks = 0; ks < KSTEPS; ++ks) {
      u32x4 af = ap[4 * ks];
      acc = __builtin_amdgcn_mfma_f32_16x16x32_bf16(
          __builtin_bit_cast(bf16x8, atr[ks]), __builtin_bit_cast(bf16x8, af),
          acc, 0, 0, 0);
    }

    // --- scales + log-lik (wave 0 tail while others finish k-loop)
    if (tid < MB) {
      float s = 0.f;
#pragma unroll
      for (int c = 0; c < 13; ++c) s += srow[tid][c];
      ll += logf(s);
      inv_lds[tid] = 1.0f / s;
      chars[tid] = ch;
    }
    __syncthreads();  // inv/chars ready

    // --- epilogue: lane holds f[brow=lcol][n0w+4*lrow .. +3]
    const f32x4 ev = *(const f32x4*)(Bt + (size_t)chars[lcol] * BTS + n0w + 4 * lrow);
    const float inv = inv_lds[lcol];
    float rs = 0.f;
    u64 hv = 0;
#pragma unroll
    for (int i = 0; i < 4; ++i) {
      float v = acc[i] * ev[i] * inv;
      rs += v;
      hv |= (u64)f2bf(v) << (16 * i);
    }
    ast8(wbuf8 + (size_t)(bb * MB + lcol) * RQ + (n0w >> 2) + lrow, hv);
    rs += __shfl_xor(rs, 16);
    rs += __shfl_xor(rs, 32);
    if (lane < 16) spart[lane][wv] = rs;
    __syncthreads();  // spart visible + ALL waves' alpha stores drained (vmcnt0)

    // --- publish (s5 | tag): the store IS the arrival signal
    if (tid < MB) {
      float s5 = spart[tid][0] + spart[tid][1] + spart[tid][2] +
                 spart[tid][3] + spart[tid][4];
      union { float f; unsigned u; } w; w.f = s5;
      ast8(psumE + ((size_t)wri * NBB + bb) * (NSL * MB) + sl * MB + tid,
           (u64)w.u | ((u64)(unsigned)t << 32));
    }
  }

  if (sl == 0 && tid < MB) {
    const u64* tb = psumE + ((size_t)((TT - 1) % 3) * NBB + bb) * (NSL * MB);
    float s = 0.f;
    for (int c = 0; c < NSL; ++c) s += spin_tag(tb + c * MB + tid, (unsigned)(TT - 1));
    out[bb * MB + tid] = ll + logf(s);
  }
}

extern "C" void kernel_launch(void* const* d_in, const int* in_sizes, int n_in,
                              void* d_out, int out_size, void* d_ws, size_t ws_size,
                              hipStream_t stream) {
  const int* seq = (const int*)d_in[0];
  const float* Al = (const float*)d_in[1];
  const float* Bl = (const float*)d_in[2];
  const float* il = (const float*)d_in[3];
  float* out = (float*)d_out;

  char* ws = (char*)d_ws;
  unsigned short* At = (unsigned short*)ws;               // 1040*1056*2 = 2,196,480
  size_t off_bt = (size_t)NP * KP * 2;
  float* Bt = (float*)(ws + off_bt);                      // 26*1040*4 = 108,160
  size_t off_ip = off_bt + (size_t)SS * BTS * 4;
  float* ip = (float*)(ws + off_ip);                      // 1040*4
  size_t off_buf = off_ip + (size_t)NP * 4;
  unsigned short* bufB = (unsigned short*)(ws + off_buf); // 3*256*1056*2 = 1,622,016
  size_t off_ps = off_buf + (size_t)3 * BUFN * 2;
  u64* psumE = (u64*)(ws + off_ps);                       // 3*3328*8 = 79,872
  size_t total = off_ps + (size_t)3 * PSE * 8;
  int n16 = (int)((total + 15) / 16);

  k_zero<<<(n16 + 255) / 256, 256, 0, stream>>>((u32x4*)ws, n16);
  k_prep_init<<<1, 1024, 0, stream>>>(il, ip);
  k_prep_B<<<(QQ + 255) / 256, 256, 0, stream>>>(Bl, Bt);
  k_prep_A<<<QQ, 256, 0, stream>>>(Al, At);
  k_init_step<<<NB, 256, 0, stream>>>(seq, ip, Bt, bufB, psumE);

  void* args[] = {(void*)&seq, (void*)&At, (void*)&Bt, (void*)&bufB,
                  (void*)&psumE, (void*)&out};
  hipLaunchCooperativeKernel((void*)k_hmm_coop, dim3(NBB * NSL), dim3(CBLK),
                             args, 0, stream);
}

// Round 7
// 1547.937 us; speedup vs baseline: 2.1709x; 2.1709x over previous
//
#include <hip/hip_runtime.h>
#include <math.h>

typedef __bf16 bf16x8 __attribute__((ext_vector_type(8)));
typedef float f32x4 __attribute__((ext_vector_type(4)));
typedef unsigned int u32x4 __attribute__((ext_vector_type(4)));
typedef unsigned long long u64;

constexpr int QQ = 1027;   // states
constexpr int SS = 26;     // alphabet
constexpr int TT = 512;    // sequence length
constexpr int NB = 256;    // batch
constexpr int KP = 1056;   // K padded (mult of 32)
constexpr int NP = 1040;   // N padded (65 tiles of 16)
constexpr int BTS = 1040;  // Bt row stride (floats)
constexpr int NSL = 13;    // N slices (5 tiles = 80 cols each)
constexpr int NBB = 16;    // batch blocks
constexpr int MB = 16;     // batch rows per block
constexpr int NWV = 5;     // waves per WG (1 N-tile each)
constexpr int CBLK = NWV * 64;       // 320
constexpr int KSTEPS = KP / 32;      // 33
constexpr int BUFN = NB * KP;        // bf16 elems per alpha buffer
constexpr int RQ = KP / 4;           // 264 u64 per alpha row
constexpr int LQ = RQ + 2;           // 266 u64 LDS row stride
constexpr int TOTQ = MB * RQ;        // 4224 u64 per batch-block alpha
constexpr int NLD = TOTQ / CBLK;     // 13 full loads per thread
constexpr int NREM = TOTQ - NLD * CBLK;  // 64 threads do one more
constexpr int PSE = NBB * NSL * MB;  // 3328 tag-u64 per slot

__device__ __forceinline__ unsigned short f2bf(float f) {
  union { float f; unsigned u; } v; v.f = f;
  return (unsigned short)((v.u + 0x7fffu + ((v.u >> 16) & 1u)) >> 16);
}

__device__ __forceinline__ u64 ald8(const u64* p) {
  return __hip_atomic_load((u64*)p, __ATOMIC_RELAXED, __HIP_MEMORY_SCOPE_AGENT);
}
__device__ __forceinline__ void ast8(u64* p, u64 v) {
  __hip_atomic_store(p, v, __ATOMIC_RELAXED, __HIP_MEMORY_SCOPE_AGENT);
}

// Spin until the (s5|tag) word carries tag==texp; returns s5.
__device__ __forceinline__ float spin_tag(const u64* p, unsigned texp) {
  u64 v = ald8(p);
  while ((unsigned)(v >> 32) != texp) {
    __builtin_amdgcn_s_sleep(1);
    v = ald8(p);
  }
  union { unsigned u; float f; } w; w.u = (unsigned)v;
  return w.f;
}

__global__ void k_zero(u32x4* p, int n) {
  int i = blockIdx.x * blockDim.x + threadIdx.x;
  if (i < n) p[i] = (u32x4){0u, 0u, 0u, 0u};
}

__global__ void k_prep_init(const float* __restrict__ il, float* __restrict__ ip) {
  __shared__ float red[1024];
  int tid = threadIdx.x;
  float m = -1e30f;
  for (int q = tid; q < QQ; q += 1024) m = fmaxf(m, il[q]);
  red[tid] = m; __syncthreads();
  for (int off = 512; off > 0; off >>= 1) {
    if (tid < off) red[tid] = fmaxf(red[tid], red[tid + off]);
    __syncthreads();
  }
  m = red[0]; __syncthreads();
  float s = 0.f;
  for (int q = tid; q < QQ; q += 1024) s += expf(il[q] - m);
  red[tid] = s; __syncthreads();
  for (int off = 512; off > 0; off >>= 1) {
    if (tid < off) red[tid] += red[tid + off];
    __syncthreads();
  }
  s = red[0];
  float inv = 1.0f / s;
  for (int q = tid; q < QQ; q += 1024) ip[q] = expf(il[q] - m) * inv;
}

__global__ void k_prep_B(const float* __restrict__ bl, float* __restrict__ bt) {
  int q = blockIdx.x * blockDim.x + threadIdx.x;
  if (q >= QQ) return;
  const float* row = bl + (size_t)q * SS;
  float m = -1e30f;
  for (int c = 0; c < SS; ++c) m = fmaxf(m, row[c]);
  float s = 0.f;
  for (int c = 0; c < SS; ++c) s += expf(row[c] - m);
  float inv = 1.0f / s;
  for (int c = 0; c < SS; ++c) bt[c * BTS + q] = expf(row[c] - m) * inv;
}

// Row r of A -> column r of A^T[n][k] (bf16)
__global__ void k_prep_A(const float* __restrict__ al, unsigned short* __restrict__ at) {
  int r = blockIdx.x;
  const float* row = al + (size_t)r * QQ;
  __shared__ float red[256];
  int tid = threadIdx.x;
  float m = -1e30f;
  for (int n = tid; n < QQ; n += 256) m = fmaxf(m, row[n]);
  red[tid] = m; __syncthreads();
  for (int off = 128; off > 0; off >>= 1) {
    if (tid < off) red[tid] = fmaxf(red[tid], red[tid + off]);
    __syncthreads();
  }
  m = red[0]; __syncthreads();
  float s = 0.f;
  for (int n = tid; n < QQ; n += 256) s += expf(row[n] - m);
  red[tid] = s; __syncthreads();
  for (int off = 128; off > 0; off >>= 1) {
    if (tid < off) red[tid] += red[tid + off];
    __syncthreads();
  }
  s = red[0];
  float inv = 1.0f / s;
  for (int n = tid; n < QQ; n += 256) at[(size_t)n * KP + r] = f2bf(expf(row[n] - m) * inv);
}

// f0 = init * E[:,0] (unnormalized) into buf0 + tagged per-slice row-sums (tag=0)
__global__ void k_init_step(const int* __restrict__ seq, const float* __restrict__ ip,
                            const float* __restrict__ Bt, unsigned short* __restrict__ buf0,
                            u64* __restrict__ psumE) {
  int b = blockIdx.x, tid = threadIdx.x;
  __shared__ float sp[16];
  if (tid < 16) sp[tid] = 0.f;
  __syncthreads();
  int c0 = seq[b * TT];
  for (int q = tid; q < NP; q += 256) {
    float v = ip[q] * Bt[c0 * BTS + q];   // ip[q>=QQ]=0, Bt[.,q>=QQ]=0
    buf0[(size_t)b * KP + q] = f2bf(v);
    atomicAdd(&sp[q / 80], v);
  }
  __syncthreads();
  if (tid < NSL) {
    union { float f; unsigned u; } w; w.f = sp[tid];
    psumE[(size_t)(b / MB) * (NSL * MB) + tid * MB + (b % MB)] = (u64)w.u;  // tag 0
  }
}

__global__ __launch_bounds__(CBLK, 1) void k_hmm_coop(
    const int* __restrict__ seq, const unsigned short* __restrict__ At,
    const float* __restrict__ Bt, unsigned short* __restrict__ bufB,
    u64* __restrict__ psumE, float* __restrict__ out) {
  __shared__ u64 aldsq[MB * LQ];          // 34 KB: this block's alpha (bf16)
  __shared__ float srow[MB][NSL + 1];     // per-row per-slice scale partials
  __shared__ float inv_lds[MB];
  __shared__ float spart[MB][NWV];

  const int tid = threadIdx.x, wg = blockIdx.x;
  const int bb = wg % NBB, sl = wg / NBB; // 13 slice-WGs per batch block (same XCD)
  const int lane = tid & 63, wv = tid >> 6;
  const int lrow = lane >> 4, lcol = lane & 15;
  const int n0w = (sl * NWV + wv) * 16;   // this wave's 16-col tile base
  const int ssl = tid >> 4, srw = tid & 15;  // spinner: slice=tid/16, row=tid%16

  // --- step-invariant At fragments, PINNED in VGPRs (asm redefinition
  // makes rematerialization of the loads inside the t-loop illegal)
  u32x4 atr[KSTEPS];
  {
    const u32x4* atp = (const u32x4*)(At + (size_t)(n0w + lcol) * KP + 8 * lrow);
#pragma unroll
    for (int ks = 0; ks < KSTEPS; ++ks) atr[ks] = atp[4 * ks];
#pragma unroll
    for (int ks = 0; ks < KSTEPS; ++ks) asm volatile("" : "+v"(atr[ks]));
  }

  float ll = 0.f;

  for (int t = 1; t < TT; ++t) {
    const int rd = (t - 1) % 3, wri = t % 3;
    const unsigned texp = (unsigned)(t - 1);
    const u64* tagb = psumE + ((size_t)rd * NBB + bb) * (NSL * MB);
    u64* tagw = psumE + ((size_t)wri * NBB + bb) * (NSL * MB);
    const u64* ain = (const u64*)(bufB + (size_t)rd * BUFN) + (size_t)bb * TOTQ;
    u64* wbuf8 = (u64*)(bufB + (size_t)wri * BUFN);

    // off-critical-path: per-lane char + emission quad (L2-cached, no exchange dep)
    const int ch = seq[(bb * MB + lcol) * TT + t];
    const f32x4 ev = *(const f32x4*)(Bt + (size_t)ch * BTS + n0w + 4 * lrow);

    // --- parallel spin: 208 threads watch one (slice,row) tag each
    if (tid < NSL * MB) srow[srw][ssl] = spin_tag(tagb + ssl * MB + srw, texp);
    __syncthreads();  // all tags seen -> alpha data readable at L3

    // --- bulk alpha loads, full MLP (atomics can't hoist above the barrier)
    u64 av[NLD], avx = 0;
    const u64* asrc = ain + tid;
#pragma unroll
    for (int j = 0; j < NLD; ++j) av[j] = ald8(asrc + j * CBLK);
    if (tid < NREM) avx = ald8(asrc + NLD * CBLK);

    // --- stage into LDS
#pragma unroll
    for (int j = 0; j < NLD; ++j) {
      int g = tid + j * CBLK;
      int r = g / RQ;
      aldsq[r * LQ + (g - r * RQ)] = av[j];
    }
    if (tid < NREM) {
      int g = tid + NLD * CBLK;
      int r = g / RQ;
      aldsq[r * LQ + (g - r * RQ)] = avx;
    }
    __syncthreads();

    // --- k-loop: pure ds_read + MFMA (At pinned in regs)
    const u32x4* ap = ((const u32x4*)aldsq) + lcol * (LQ / 2) + lrow;
    f32x4 acc = (f32x4){0.f, 0.f, 0.f, 0.f};
#pragma unroll
    for (int ks = 0; ks < KSTEPS; ++ks) {
      u32x4 af = ap[4 * ks];
      acc = __builtin_amdgcn_mfma_f32_16x16x32_bf16(
          __builtin_bit_cast(bf16x8, atr[ks]), __builtin_bit_cast(bf16x8, af),
          acc, 0, 0, 0);
    }

    // --- scales + log-lik (srow filled before first sync)
    if (tid < MB) {
      float s = 0.f;
#pragma unroll
      for (int c = 0; c < NSL; ++c) s += srow[tid][c];
      ll += logf(s);
      inv_lds[tid] = 1.0f / s;
    }
    __syncthreads();  // inv ready

    // --- epilogue: lane holds f[brow=lcol][n0w+4*lrow .. +3]
    const float inv = inv_lds[lcol];
    float rs = 0.f;
    u64 hv = 0;
#pragma unroll
    for (int i = 0; i < 4; ++i) {
      float v = acc[i] * ev[i] * inv;
      rs += v;
      hv |= (u64)f2bf(v) << (16 * i);
    }
    ast8(wbuf8 + (size_t)(bb * MB + lcol) * RQ + (n0w >> 2) + lrow, hv);
    rs += __shfl_xor(rs, 16);
    rs += __shfl_xor(rs, 32);
    if (lane < 16) spart[lane][wv] = rs;
    asm volatile("s_waitcnt vmcnt(0)" ::: "memory");  // own alpha stores L3-acked
    __syncthreads();  // all waves drained + spart visible

    // --- publish (s5 | tag): the store IS the arrival signal
    if (tid < MB) {
      float s5 = spart[tid][0] + spart[tid][1] + spart[tid][2] +
                 spart[tid][3] + spart[tid][4];
      union { float f; unsigned u; } w; w.f = s5;
      ast8(tagw + sl * MB + tid, (u64)w.u | ((u64)(unsigned)t << 32));
    }
  }

  // --- final scale (tag TT-1) + output
  if (sl == 0) {
    const u64* tb = psumE + ((size_t)((TT - 1) % 3) * NBB + bb) * (NSL * MB);
    if (tid < NSL * MB)
      srow[srw][ssl] = spin_tag(tb + ssl * MB + srw, (unsigned)(TT - 1));
    __syncthreads();
    if (tid < MB) {
      float s = 0.f;
#pragma unroll
      for (int c = 0; c < NSL; ++c) s += srow[tid][c];
      out[bb * MB + tid] = ll + logf(s);
    }
  }
}

extern "C" void kernel_launch(void* const* d_in, const int* in_sizes, int n_in,
                              void* d_out, int out_size, void* d_ws, size_t ws_size,
                              hipStream_t stream) {
  const int* seq = (const int*)d_in[0];
  const float* Al = (const float*)d_in[1];
  const float* Bl = (const float*)d_in[2];
  const float* il = (const float*)d_in[3];
  float* out = (float*)d_out;

  char* ws = (char*)d_ws;
  unsigned short* At = (unsigned short*)ws;               // 1040*1056*2 = 2,196,480
  size_t off_bt = (size_t)NP * KP * 2;
  float* Bt = (float*)(ws + off_bt);                      // 26*1040*4 = 108,160
  size_t off_ip = off_bt + (size_t)SS * BTS * 4;
  float* ip = (float*)(ws + off_ip);                      // 1040*4
  size_t off_buf = off_ip + (size_t)NP * 4;
  unsigned short* bufB = (unsigned short*)(ws + off_buf); // 3*256*1056*2 = 1,622,016
  size_t off_ps = off_buf + (size_t)3 * BUFN * 2;
  u64* psumE = (u64*)(ws + off_ps);                       // 3*3328*8 = 79,872
  size_t total = off_ps + (size_t)3 * PSE * 8;
  int n16 = (int)((total + 15) / 16);

  k_zero<<<(n16 + 255) / 256, 256, 0, stream>>>((u32x4*)ws, n16);
  k_prep_init<<<1, 1024, 0, stream>>>(il, ip);
  k_prep_B<<<(QQ + 255) / 256, 256, 0, stream>>>(Bl, Bt);
  k_prep_A<<<QQ, 256, 0, stream>>>(Al, At);
  k_init_step<<<NB, 256, 0, stream>>>(seq, ip, Bt, bufB, psumE);

  void* args[] = {(void*)&seq, (void*)&At, (void*)&Bt, (void*)&bufB,
                  (void*)&psumE, (void*)&out};
  hipLaunchCooperativeKernel((void*)k_hmm_coop, dim3(NBB * NSL), dim3(CBLK),
                             args, 0, stream);
}